// Round 3
// baseline (845.496 us; speedup 1.0000x reference)
//
#include <hip/hip_runtime.h>
#include <stdint.h>

// Problem constants
#define MM 32768
#define KK 1024
#define NN 4096

#define BM 128
#define BN 128
#define BK 128

typedef __attribute__((ext_vector_type(4))) float floatx4;
typedef __attribute__((ext_vector_type(8))) int intx8;

// ---- fp8 e4m3fn pack via HW cvt (RNE, OCP on gfx950) ----
__device__ __forceinline__ uint32_t pack4_fp8(float a, float b, float c, float d) {
  int v = 0;
  v = __builtin_amdgcn_cvt_pk_fp8_f32(a, b, v, false);  // bytes 0,1
  v = __builtin_amdgcn_cvt_pk_fp8_f32(c, d, v, true);   // bytes 2,3
  return (uint32_t)v;
}

// ---- async global->LDS, 16B per lane ----
__device__ __forceinline__ void gld_lds16(const void* g, void* l) {
  __builtin_amdgcn_global_load_lds(
      (const __attribute__((address_space(1))) uint32_t*)g,
      (__attribute__((address_space(3))) uint32_t*)l, 16, 0, 0);
}

// ---- quantize x: M*K fp32 -> fp8, 16 elems/thread ----
__global__ __launch_bounds__(256) void quant_x_kernel(const float* __restrict__ x,
                                                      uint8_t* __restrict__ o) {
  size_t i = ((size_t)blockIdx.x * 256 + threadIdx.x) * 16;
  const float4* xp = (const float4*)(x + i);
  float4 f0 = xp[0], f1 = xp[1], f2 = xp[2], f3 = xp[3];
  uint4 o4;
  o4.x = pack4_fp8(f0.x, f0.y, f0.z, f0.w);
  o4.y = pack4_fp8(f1.x, f1.y, f1.z, f1.w);
  o4.z = pack4_fp8(f2.x, f2.y, f2.z, f2.w);
  o4.w = pack4_fp8(f3.x, f3.y, f3.z, f3.w);
  *(uint4*)(o + i) = o4;
}

// ---- quantize + transpose w: (K,N) fp32 -> (N,K) fp8 ----
__global__ __launch_bounds__(256) void quant_w_kernel(const float* __restrict__ w,
                                                      uint8_t* __restrict__ o) {
  int n  = blockIdx.x * 256 + threadIdx.x;
  int k0 = blockIdx.y * 16;
  uint32_t p[4];
#pragma unroll
  for (int q = 0; q < 4; ++q) {
    float a = w[(size_t)(k0 + q * 4 + 0) * NN + n];
    float b = w[(size_t)(k0 + q * 4 + 1) * NN + n];
    float c = w[(size_t)(k0 + q * 4 + 2) * NN + n];
    float d = w[(size_t)(k0 + q * 4 + 3) * NN + n];
    p[q] = pack4_fp8(a, b, c, d);
  }
  *(uint4*)(o + (size_t)n * KK + k0) = make_uint4(p[0], p[1], p[2], p[3]);
}

// ---- MX-fp8 GEMM: C(M,N) = A8(M,K) * B8T(N,K)^T, fp32 out ----
// 128x128 tile / 256 threads; mfma_scale_f32_16x16x128_f8f6f4, e8m0 scale 127 (=1.0).
//
// Round-3 structure (T3 "minimum 2-phase", m248-verified pattern):
//   double-buffered LDS; per iteration: issue next tile's 8 global_load_lds
//   FIRST, then ds_read + MFMA current tile, then ONE __syncthreads() (its
//   vmcnt(0)+barrier lands after the loads had a whole compute phase in flight).
//   Race audit: stages into buf[x] only issued after the barrier that ordered
//   all reads of buf[x]; reads of buf[cur] covered by previous barrier.
//
// LDS swizzle (unchanged, verified r1/r2): 16B-granule XOR, LDS(row,g) holds
// global granule g ^ (row&7); linear LDS dest (global_load_lds constraint),
// pre-swizzled global source column, swizzled read offsets.
//
// Epilogue (new): swapped-operand MFMA -> mfma(bf, af): D reg-dim |-> n,
// lane-dim |-> m, so each lane's 4 acc floats are 4 consecutive n columns
// -> 16 float4 stores/lane instead of 64 scalar stores.
__global__ __launch_bounds__(256) void gemm_fp8_kernel(const uint8_t* __restrict__ A,
                                                       const uint8_t* __restrict__ Bt,
                                                       float* __restrict__ C) {
  __shared__ __align__(16) uint8_t As[2][BM * BK];  // 2 x 16 KB
  __shared__ __align__(16) uint8_t Bs[2][BN * BK];  // 2 x 16 KB

  const int tid  = threadIdx.x;
  const int lane = tid & 63;
  const int wv   = tid >> 6;
  const int wr   = (wv >> 1) * 64;  // wave row offset in tile
  const int wc   = (wv & 1) * 64;   // wave col offset in tile
  const int quad = lane >> 4;
  const int r    = lane & 15;

  // XCD-aware chunked swizzle (m157): 8192 wgs, 8 XCDs -> 1024-wg chunks.
  const int lid = (int)blockIdx.x;                 // 0..8191
  const int swz = (lid & 7) * 1024 + (lid >> 3);   // bijective (8192 % 8 == 0)
  const long bm = (long)(swz >> 5) * BM;           // 256 m-tiles
  const long bn = (long)(swz & 31) * BN;           // 32 n-tiles

  // staging: thread t fills LDS bytes [t*16, t*16+16) = slot (row=t>>3, g=t&7);
  // source column = (g ^ (row&7))*16. (row&7) invariant under +32-row blocks.
  const int sr   = tid >> 3;  // 0..31
  const int sg   = tid & 7;
  const int scol = (sg ^ (sr & 7)) << 4;
  const uint8_t* Ag = A + (bm + sr) * KK + scol;
  const uint8_t* Bg = Bt + (bn + sr) * KK + scol;
  const int loff = tid * 16;

  floatx4 acc[4][4] = {};

  // read-side swizzle key: fragment rows are (wr|wc) + i*16 + r, and
  // (wr + i*16) % 16 == 0, so (row&7) == (r&7) for every row this lane reads.
  const int e  = r & 7;
  const int g0 = (((quad << 1) | 0) ^ e) << 4;  // byte offset of k-half 0
  const int g1 = (((quad << 1) | 1) ^ e) << 4;  // byte offset of k-half 1

  // prologue: stage tile 0 into buf 0
#pragma unroll
  for (int blk = 0; blk < 4; ++blk) {
    gld_lds16(Ag + (size_t)blk * 32 * KK, &As[0][blk * 4096 + loff]);
    gld_lds16(Bg + (size_t)blk * 32 * KK, &Bs[0][blk * 4096 + loff]);
  }
  __syncthreads();

  for (int t = 0; t < 8; ++t) {
    const int cur = t & 1;
    // issue next tile's stages FIRST (they fly during this tile's compute)
    if (t < 7) {
      const size_t k0 = (size_t)(t + 1) * BK;
#pragma unroll
      for (int blk = 0; blk < 4; ++blk) {
        gld_lds16(Ag + k0 + (size_t)blk * 32 * KK, &As[cur ^ 1][blk * 4096 + loff]);
        gld_lds16(Bg + k0 + (size_t)blk * 32 * KK, &Bs[cur ^ 1][blk * 4096 + loff]);
      }
    }

    intx8 af[4], bf[4];
#pragma unroll
    for (int i = 0; i < 4; ++i) {
      const uint8_t* pa = &As[cur][(wr + i * 16 + r) * BK];
      union { intx8 v; int4 q[2]; } u;
      u.q[0] = *(const int4*)(pa + g0);
      u.q[1] = *(const int4*)(pa + g1);
      af[i] = u.v;
    }
#pragma unroll
    for (int j = 0; j < 4; ++j) {
      const uint8_t* pb = &Bs[cur][(wc + j * 16 + r) * BK];
      union { intx8 v; int4 q[2]; } u;
      u.q[0] = *(const int4*)(pb + g0);
      u.q[1] = *(const int4*)(pb + g1);
      bf[j] = u.v;
    }
#pragma unroll
    for (int i = 0; i < 4; ++i)
#pragma unroll
      for (int j = 0; j < 4; ++j)
        // swapped operands: D reg-dim -> n (B rows), lane-dim -> m (A rows).
        // scales = e8m0 127 = 2^0 = 1.0 on both operands -> exact fp8 products.
        acc[i][j] = __builtin_amdgcn_mfma_scale_f32_16x16x128_f8f6f4(
            bf[j], af[i], acc[i][j], 0, 0, 0, 127, 0, 127);

    if (t < 7) __syncthreads();  // vmcnt(0)+lgkmcnt(0)+barrier: next buf ready, cur buf free
  }

  // epilogue: lane holds m = wr + i*16 + r, n = wc + j*16 + quad*4 + v (v=reg)
#pragma unroll
  for (int i = 0; i < 4; ++i) {
    const long row = bm + wr + i * 16 + r;
    float* crow = C + row * NN + bn + wc + quad * 4;
#pragma unroll
    for (int j = 0; j < 4; ++j)
      *(floatx4*)(crow + j * 16) = acc[i][j];
  }
}

extern "C" void kernel_launch(void* const* d_in, const int* in_sizes, int n_in,
                              void* d_out, int out_size, void* d_ws, size_t ws_size,
                              hipStream_t stream) {
  const float* x = (const float*)d_in[0];  // (M,K) fp32
  const float* w = (const float*)d_in[1];  // (K,N) fp32
  float* out = (float*)d_out;              // (M,N) fp32

  uint8_t* x8  = (uint8_t*)d_ws;                    // 32 MB
  uint8_t* w8t = x8 + (size_t)MM * KK;              // 4 MB, (N,K)

  quant_x_kernel<<<(MM * (size_t)KK) / (256 * 16), 256, 0, stream>>>(x, x8);
  quant_w_kernel<<<dim3(NN / 256, KK / 16), 256, 0, stream>>>(w, w8t);
  gemm_fp8_kernel<<<(MM / BM) * (NN / BN), 256, 0, stream>>>(x8, w8t, out);
}

// Round 5
// 824.583 us; speedup vs baseline: 1.0254x; 1.0254x over previous
//
#include <hip/hip_runtime.h>
#include <stdint.h>

// Problem constants
#define MM 32768
#define KK 1024
#define NN 4096

#define BM 128
#define BN 128
#define BK 128

typedef __attribute__((ext_vector_type(4))) float floatx4;
typedef __attribute__((ext_vector_type(8))) int intx8;

// ---- fp8 e4m3fn pack via HW cvt (RNE, OCP on gfx950) ----
__device__ __forceinline__ uint32_t pack4_fp8(float a, float b, float c, float d) {
  int v = 0;
  v = __builtin_amdgcn_cvt_pk_fp8_f32(a, b, v, false);  // bytes 0,1
  v = __builtin_amdgcn_cvt_pk_fp8_f32(c, d, v, true);   // bytes 2,3
  return (uint32_t)v;
}

// ---- async global->LDS, 16B per lane ----
__device__ __forceinline__ void gld_lds16(const void* g, void* l) {
  __builtin_amdgcn_global_load_lds(
      (const __attribute__((address_space(1))) uint32_t*)g,
      (__attribute__((address_space(3))) uint32_t*)l, 16, 0, 0);
}

// ---- quantize x: M*K fp32 -> fp8, 16 elems/thread ----
__global__ __launch_bounds__(256) void quant_x_kernel(const float* __restrict__ x,
                                                      uint8_t* __restrict__ o) {
  size_t i = ((size_t)blockIdx.x * 256 + threadIdx.x) * 16;
  const float4* xp = (const float4*)(x + i);
  float4 f0 = xp[0], f1 = xp[1], f2 = xp[2], f3 = xp[3];
  uint4 o4;
  o4.x = pack4_fp8(f0.x, f0.y, f0.z, f0.w);
  o4.y = pack4_fp8(f1.x, f1.y, f1.z, f1.w);
  o4.z = pack4_fp8(f2.x, f2.y, f2.z, f2.w);
  o4.w = pack4_fp8(f3.x, f3.y, f3.z, f3.w);
  *(uint4*)(o + i) = o4;
}

// ---- quantize + transpose w: (K,N) fp32 -> (N,K) fp8 ----
__global__ __launch_bounds__(256) void quant_w_kernel(const float* __restrict__ w,
                                                      uint8_t* __restrict__ o) {
  int n  = blockIdx.x * 256 + threadIdx.x;
  int k0 = blockIdx.y * 16;
  uint32_t p[4];
#pragma unroll
  for (int q = 0; q < 4; ++q) {
    float a = w[(size_t)(k0 + q * 4 + 0) * NN + n];
    float b = w[(size_t)(k0 + q * 4 + 1) * NN + n];
    float c = w[(size_t)(k0 + q * 4 + 2) * NN + n];
    float d = w[(size_t)(k0 + q * 4 + 3) * NN + n];
    p[q] = pack4_fp8(a, b, c, d);
  }
  *(uint4*)(o + (size_t)n * KK + k0) = make_uint4(p[0], p[1], p[2], p[3]);
}

// ---- MX-fp8 GEMM: C(M,N) = A8(M,K) * B8T(N,K)^T, fp32 out ----
// 128x128 tile / 256 threads; mfma_scale_f32_16x16x128_f8f6f4, e8m0 scale 127 (=1.0).
//
// Schedule (T4 counted-vmcnt + T5 setprio; raw s_barrier, NO __syncthreads):
//   per iter t:
//     A: issue 8 global_load_lds (tile t+1 -> buf[cur^1])
//     B: s_waitcnt vmcnt(8)   <- waits ONLY the previous batch (tile t); the 8
//        just-issued loads stay in flight across the barrier (never drain to 0
//        in-loop — m218: counted-vs-drain0 = +38-73%)
//     C: s_barrier            <- tile t's data visible block-wide
//     D: ds_read frags(buf[cur]); lgkmcnt(0); sched_barrier(0) [rule 18]; s_barrier
//        <- every wave's reads are in regs => buf[cur] free for overwrite at t+1
//     E: setprio(1); 16 MFMA; setprio(0)   [T5: phase split gives scheduler roles]
//   Race ledger: STAGE->buf[x] at t ordered after t-1's D-barrier (all reads of
//   buf[x] in regs); reads of buf[cur] ordered after C-barrier (all waves passed
//   vmcnt(8) => batch t landed). Control flow wave-uniform; barrier count uniform.
//
// LDS swizzle (verified r1-r3): 16B-granule XOR, LDS(row,g) holds global granule
// g ^ (row&7); linear LDS dest, pre-swizzled global source, swizzled read offsets.
// Epilogue (verified r3): swapped-operand MFMA -> lane holds 4 consecutive n cols
// -> float4 stores.
__global__ __launch_bounds__(256) void gemm_fp8_kernel(const uint8_t* __restrict__ A,
                                                       const uint8_t* __restrict__ Bt,
                                                       float* __restrict__ C) {
  __shared__ __align__(16) uint8_t As[2][BM * BK];  // 2 x 16 KB
  __shared__ __align__(16) uint8_t Bs[2][BN * BK];  // 2 x 16 KB

  const int tid  = threadIdx.x;
  const int lane = tid & 63;
  const int wv   = tid >> 6;
  const int wr   = (wv >> 1) * 64;  // wave row offset in tile
  const int wc   = (wv & 1) * 64;   // wave col offset in tile
  const int quad = lane >> 4;
  const int r    = lane & 15;

  // XCD-aware chunked swizzle (m157): 8192 wgs, 8 XCDs -> 1024-wg chunks.
  const int lid = (int)blockIdx.x;                 // 0..8191
  const int swz = (lid & 7) * 1024 + (lid >> 3);   // bijective (8192 % 8 == 0)
  const long bm = (long)(swz >> 5) * BM;           // 256 m-tiles
  const long bn = (long)(swz & 31) * BN;           // 32 n-tiles

  // staging: thread t fills LDS bytes [t*16, t*16+16) = slot (row=t>>3, g=t&7);
  // source column = (g ^ (row&7))*16. (row&7) invariant under +32-row blocks.
  const int sr   = tid >> 3;  // 0..31
  const int sg   = tid & 7;
  const int scol = (sg ^ (sr & 7)) << 4;
  const uint8_t* Ag = A + (bm + sr) * KK + scol;
  const uint8_t* Bg = Bt + (bn + sr) * KK + scol;
  const int loff = tid * 16;

  floatx4 acc[4][4] = {};

  // read-side swizzle key: fragment rows are (wr|wc) + i*16 + r, and
  // (wr + i*16) % 16 == 0, so (row&7) == (r&7) for every row this lane reads.
  const int e  = r & 7;
  const int g0 = (((quad << 1) | 0) ^ e) << 4;  // byte offset of k-half 0
  const int g1 = (((quad << 1) | 1) ^ e) << 4;  // byte offset of k-half 1

  // prologue: stage tile 0 into buf 0; one-time full drain
#pragma unroll
  for (int blk = 0; blk < 4; ++blk) {
    gld_lds16(Ag + (size_t)blk * 32 * KK, &As[0][blk * 4096 + loff]);
    gld_lds16(Bg + (size_t)blk * 32 * KK, &Bs[0][blk * 4096 + loff]);
  }
  asm volatile("s_waitcnt vmcnt(0)" ::: "memory");
  __builtin_amdgcn_s_barrier();

#pragma unroll
  for (int t = 0; t < 8; ++t) {
    const int cur = t & 1;

    // A: issue next tile's stages (fly across the whole iteration)
    if (t < 7) {
      const size_t k0 = (size_t)(t + 1) * BK;
#pragma unroll
      for (int blk = 0; blk < 4; ++blk) {
        gld_lds16(Ag + k0 + (size_t)blk * 32 * KK, &As[cur ^ 1][blk * 4096 + loff]);
        gld_lds16(Bg + k0 + (size_t)blk * 32 * KK, &Bs[cur ^ 1][blk * 4096 + loff]);
      }
      // B: counted wait — previous batch (tile t) landed; new 8 stay in flight
      asm volatile("s_waitcnt vmcnt(8)" ::: "memory");
    } else {
      asm volatile("s_waitcnt vmcnt(0)" ::: "memory");  // last tile: nothing newer
    }
    // C: tile t visible block-wide
    __builtin_amdgcn_s_barrier();
    __builtin_amdgcn_sched_barrier(0);

    // D: fragment reads from buf[cur]
    intx8 af[4], bf[4];
#pragma unroll
    for (int i = 0; i < 4; ++i) {
      const uint8_t* pa = &As[cur][(wr + i * 16 + r) * BK];
      union { intx8 v; int4 q[2]; } u;
      u.q[0] = *(const int4*)(pa + g0);
      u.q[1] = *(const int4*)(pa + g1);
      af[i] = u.v;
    }
#pragma unroll
    for (int j = 0; j < 4; ++j) {
      const uint8_t* pb = &Bs[cur][(wc + j * 16 + r) * BK];
      union { intx8 v; int4 q[2]; } u;
      u.q[0] = *(const int4*)(pb + g0);
      u.q[1] = *(const int4*)(pb + g1);
      bf[j] = u.v;
    }
    asm volatile("s_waitcnt lgkmcnt(0)" ::: "memory");
    __builtin_amdgcn_sched_barrier(0);  // rule #18: pin MFMA below the lgkmcnt
    __builtin_amdgcn_s_barrier();       // buf[cur] free for next iter's STAGE

    // E: MFMA cluster (register-only); T5 priority hint
    __builtin_amdgcn_s_setprio(1);
#pragma unroll
    for (int i = 0; i < 4; ++i)
#pragma unroll
      for (int j = 0; j < 4; ++j)
        // swapped operands: D reg-dim -> n, lane-dim -> m; e8m0 scale 127 = 1.0
        acc[i][j] = __builtin_amdgcn_mfma_scale_f32_16x16x128_f8f6f4(
            bf[j], af[i], acc[i][j], 0, 0, 0, 127, 0, 127);
    __builtin_amdgcn_s_setprio(0);
  }

  // epilogue: lane holds m = wr + i*16 + r, n = wc + j*16 + quad*4 + v (v=reg)
#pragma unroll
  for (int i = 0; i < 4; ++i) {
    const long row = bm + wr + i * 16 + r;
    float* crow = C + row * NN + bn + wc + quad * 4;
#pragma unroll
    for (int j = 0; j < 4; ++j)
      *(floatx4*)(crow + j * 16) = acc[i][j];
  }
}

extern "C" void kernel_launch(void* const* d_in, const int* in_sizes, int n_in,
                              void* d_out, int out_size, void* d_ws, size_t ws_size,
                              hipStream_t stream) {
  const float* x = (const float*)d_in[0];  // (M,K) fp32
  const float* w = (const float*)d_in[1];  // (K,N) fp32
  float* out = (float*)d_out;              // (M,N) fp32

  uint8_t* x8  = (uint8_t*)d_ws;                    // 32 MB
  uint8_t* w8t = x8 + (size_t)MM * KK;              // 4 MB, (N,K)

  quant_x_kernel<<<(MM * (size_t)KK) / (256 * 16), 256, 0, stream>>>(x, x8);
  quant_w_kernel<<<dim3(NN / 256, KK / 16), 256, 0, stream>>>(w, w8t);
  gemm_fp8_kernel<<<(MM / BM) * (NN / BN), 256, 0, stream>>>(x8, w8t, out);
}